// Round 1
// baseline (337.437 us; speedup 1.0000x reference)
//
#include <hip/hip_runtime.h>
#include <stdint.h>

#define CH    256
#define HWsz  3136
#define NIMG  32
#define COLS  (NIMG * HWsz)   // 100352
#define KB    32
#define TN    64

typedef float  f32x4  __attribute__((ext_vector_type(4)));
typedef __bf16 bf16x8 __attribute__((ext_vector_type(8)));

struct Stats {
  float mnsum[CH];
  float mn[CH];
  float poff[CH];
  unsigned dminK[CH];
  unsigned dmaxK[CH];
  float dminF[CH];
  float scaleF[CH];
  float invF[CH];
  float qsum[CH];
  float corr[CH];
  unsigned short u_bf[CH * CH];   // u row-major (A for GEMM2)
  unsigned short uT_bf[CH * CH];  // u transposed (A for GEMM1)
};

__device__ __forceinline__ unsigned short f2bf(float f) {
  union { float f; unsigned u; } v; v.f = f;
  unsigned r = v.u + 0x7fffu + ((v.u >> 16) & 1u);  // RNE
  return (unsigned short)(r >> 16);
}
__device__ __forceinline__ float bf2f(unsigned short b) {
  union { unsigned u; float f; } v; v.u = ((unsigned)b) << 16;
  return v.f;
}
__device__ __forceinline__ unsigned fkey(float f) {  // monotonic float->uint
  unsigned u = __float_as_uint(f);
  return (u & 0x80000000u) ? ~u : (u | 0x80000000u);
}
__device__ __forceinline__ float funkey(unsigned k) {
  unsigned u = (k & 0x80000000u) ? (k & 0x7fffffffu) : ~k;
  return __uint_as_float(u);
}
__device__ __forceinline__ float dq(float v, float dmin, float sc, float inv) {
  return sc == 0.f ? v : fmaf(rintf((v - dmin) * sc), inv, dmin);
}

// ---- tiny kernels -------------------------------------------------------
__global__ void k_init(const float* __restrict__ u, Stats* st) {
  int b = blockIdx.x, t = threadIdx.x;
  st->u_bf[b * CH + t]  = f2bf(u[b * CH + t]);
  st->uT_bf[b * CH + t] = f2bf(u[t * CH + b]);
  if (b == 0) {
    st->mnsum[t] = 0.f;
    st->qsum[t]  = 0.f;
    st->dminK[t] = 0xFFFFFFFFu;
    st->dmaxK[t] = 0u;
  }
}

__global__ __launch_bounds__(256) void k_relusum(const float* __restrict__ x, Stats* st) {
  int row = blockIdx.x;            // n*CH + c
  int c = row & (CH - 1);
  const float4* xr = (const float4*)(x + (size_t)row * HWsz);
  float s = 0.f;
  for (int i = threadIdx.x; i < HWsz / 4; i += 256) {
    float4 v = xr[i];
    s += fmaxf(v.x, 0.f) + fmaxf(v.y, 0.f) + fmaxf(v.z, 0.f) + fmaxf(v.w, 0.f);
  }
  for (int off = 32; off; off >>= 1) s += __shfl_down(s, off);
  __shared__ float w4[4];
  int lane = threadIdx.x & 63, wv = threadIdx.x >> 6;
  if (!lane) w4[wv] = s;
  __syncthreads();
  if (threadIdx.x == 0) atomicAdd(&st->mnsum[c], w4[0] + w4[1] + w4[2] + w4[3]);
}

__global__ void k_mn_poff(const float* __restrict__ u, Stats* st) {
  int t = threadIdx.x;
  __shared__ float smn[CH];
  float mn = st->mnsum[t] * (1.f / COLS);
  st->mn[t] = mn;
  smn[t] = mn;
  __syncthreads();
  float acc = 0.f;
  for (int c = 0; c < CH; ++c) acc += u[c * CH + t] * smn[c];
  st->poff[t] = acc;
}

__global__ void k_finalize(Stats* st) {
  int t = threadIdx.x;
  float dmin = funkey(st->dminK[t]);
  float dmax = funkey(st->dmaxK[t]);
  float rng = dmax - dmin;
  float sc = 0.f, inv = 0.f;
  if (rng != 0.f) { sc = 255.f / rng; inv = rng / 255.f; }
  st->dminF[t] = dmin; st->scaleF[t] = sc; st->invF[t] = inv;
}

__global__ void k_corr(const float* __restrict__ u, Stats* st) {
  int t = threadIdx.x;
  __shared__ float qm[CH];
  qm[t] = st->qsum[t] * (1.f / COLS);
  __syncthreads();
  float acc = 0.f;
  for (int r = 0; r < CH; ++r) acc += u[t * CH + r] * qm[r];
  st->corr[t] = st->mn[t] - acc;
}

// ---- GEMM1: pq = clamp(uT @ relu(x) - poff), store pq, global min/max ----
template <bool PQ_BF16>
__global__ __launch_bounds__(256) void k_gemm1(const float* __restrict__ x,
                                               const float* __restrict__ clampv,
                                               Stats* __restrict__ st,
                                               void* __restrict__ pqbuf) {
  __shared__ __align__(16) unsigned ldsB[TN * 20];  // 64 j-rows * 20 u32 (swizzled)
  __shared__ float smin[CH];
  __shared__ float smax[CH];

  const int blk = blockIdx.x;
  const int n   = blk / (HWsz / TN);
  const int hw0 = (blk % (HWsz / TN)) * TN;
  const int t = threadIdx.x;
  const int lane = t & 63, wv = t >> 6;
  const int g = t & 15, cpair = t >> 4;
  const int sq = cpair >> 2, c2 = cpair & 3;   // staging quad(=wave), low bits
  const int q = lane >> 4, r15 = lane & 15;    // compute roles

  const float* xim = x + (size_t)n * CH * HWsz;
  const unsigned short* uT = st->uT_bf;

  f32x4 acc[4][4] = {};

  for (int kc = 0; kc < CH / KB; ++kc) {
    __syncthreads();
    {
      const float* r0 = xim + (size_t)(kc * KB + 2 * cpair) * HWsz + hw0 + 4 * g;
      const float4 va = *(const float4*)r0;
      const float4 vb = *(const float4*)(r0 + HWsz);
      const float a0[4] = {va.x, va.y, va.z, va.w};
      const float b0[4] = {vb.x, vb.y, vb.z, vb.w};
#pragma unroll
      for (int i = 0; i < 4; ++i) {
        const int j = 4 * g + i;
        const unsigned lo = f2bf(fmaxf(a0[i], 0.f));
        const unsigned hi = f2bf(fmaxf(b0[i], 0.f));
        ldsB[j * 20 + ((sq ^ ((j >> 3) & 3)) << 2) + c2] = lo | (hi << 16);
      }
    }
    __syncthreads();

    bf16x8 afr[4];
#pragma unroll
    for (int mt = 0; mt < 4; ++mt) {
      const int row = 64 * wv + 16 * mt + r15;
      afr[mt] = *(const bf16x8*)(uT + row * CH + kc * KB + q * 8);
    }
#pragma unroll
    for (int nt = 0; nt < 4; ++nt) {
      const int j = nt * 16 + r15;
      const bf16x8 bfr = *(const bf16x8*)((const unsigned short*)ldsB +
                                          (size_t)j * 40 + ((q ^ ((j >> 3) & 3)) << 3));
#pragma unroll
      for (int mt = 0; mt < 4; ++mt)
        acc[mt][nt] = __builtin_amdgcn_mfma_f32_16x16x32_bf16(afr[mt], bfr, acc[mt][nt], 0, 0, 0);
    }
  }

#pragma unroll
  for (int mt = 0; mt < 4; ++mt) {
#pragma unroll
    for (int reg = 0; reg < 4; ++reg) {
      const int row = 64 * wv + 16 * mt + 4 * q + reg;
      const float po = st->poff[row];
      const float cv = clampv[row];
      float mnv = 1e30f, mxv = -1e30f;
      const size_t obase = ((size_t)(n * CH + row)) * HWsz + hw0;
#pragma unroll
      for (int nt = 0; nt < 4; ++nt) {
        float v = acc[mt][nt][reg] - po;
        v = fminf(fmaxf(v, -cv), cv);
        mnv = fminf(mnv, v);
        mxv = fmaxf(mxv, v);
        const int jl = nt * 16 + r15;
        if (PQ_BF16) ((unsigned short*)pqbuf)[obase + jl] = f2bf(v);
        else         ((float*)pqbuf)[obase + jl] = v;
      }
#pragma unroll
      for (int m = 8; m; m >>= 1) {
        mnv = fminf(mnv, __shfl_xor(mnv, m));
        mxv = fmaxf(mxv, __shfl_xor(mxv, m));
      }
      if (r15 == 0) { smin[row] = mnv; smax[row] = mxv; }
    }
  }
  __syncthreads();
  atomicMin(&st->dminK[t], fkey(smin[t]));
  atomicMax(&st->dmaxK[t], fkey(smax[t]));
}

// ---- qsum: per-row sum of dequantized q ---------------------------------
template <bool PQ_BF16>
__global__ __launch_bounds__(256) void k_qsum(const void* __restrict__ pqbuf,
                                              Stats* __restrict__ st) {
  const int blk = blockIdx.x;  // n*CH + r
  const int r = blk & (CH - 1);
  const float dmin = st->dminF[r], sc = st->scaleF[r], inv = st->invF[r];
  const size_t base = (size_t)blk * HWsz;
  float s = 0.f;
  if (PQ_BF16) {
    const ushort4* p = (const ushort4*)((const unsigned short*)pqbuf + base);
    for (int i = threadIdx.x; i < HWsz / 4; i += 256) {
      const ushort4 v = p[i];
      s += dq(bf2f(v.x), dmin, sc, inv) + dq(bf2f(v.y), dmin, sc, inv) +
           dq(bf2f(v.z), dmin, sc, inv) + dq(bf2f(v.w), dmin, sc, inv);
    }
  } else {
    const float4* p = (const float4*)((const float*)pqbuf + base);
    for (int i = threadIdx.x; i < HWsz / 4; i += 256) {
      const float4 v = p[i];
      s += dq(v.x, dmin, sc, inv) + dq(v.y, dmin, sc, inv) +
           dq(v.z, dmin, sc, inv) + dq(v.w, dmin, sc, inv);
    }
  }
  for (int off = 32; off; off >>= 1) s += __shfl_down(s, off);
  __shared__ float w4[4];
  int lane = threadIdx.x & 63, wv = threadIdx.x >> 6;
  if (!lane) w4[wv] = s;
  __syncthreads();
  if (threadIdx.x == 0) atomicAdd(&st->qsum[r], w4[0] + w4[1] + w4[2] + w4[3]);
}

// ---- GEMM2: out = u @ q + corr ------------------------------------------
template <bool PQ_BF16>
__global__ __launch_bounds__(256) void k_gemm2(const void* __restrict__ pqbuf,
                                               Stats* __restrict__ st,
                                               float* __restrict__ out) {
  __shared__ __align__(16) unsigned ldsB[TN * 20];

  const int blk = blockIdx.x;
  const int n   = blk / (HWsz / TN);
  const int hw0 = (blk % (HWsz / TN)) * TN;
  const int t = threadIdx.x;
  const int lane = t & 63, wv = t >> 6;
  const int g = t & 15, cpair = t >> 4;
  const int sq = cpair >> 2, c2 = cpair & 3;
  const int q = lane >> 4, r15 = lane & 15;

  const unsigned short* uA = st->u_bf;
  f32x4 acc[4][4] = {};

  for (int kc = 0; kc < CH / KB; ++kc) {
    __syncthreads();
    {
      const int R0 = kc * KB + 2 * cpair;
      const float d0 = st->dminF[R0],     s0 = st->scaleF[R0],     i0 = st->invF[R0];
      const float d1 = st->dminF[R0 + 1], s1 = st->scaleF[R0 + 1], i1 = st->invF[R0 + 1];
      const size_t b0 = ((size_t)(n * CH + R0)) * HWsz + hw0 + 4 * g;
      float a0[4], b1[4];
      if (PQ_BF16) {
        const ushort4 va = *(const ushort4*)((const unsigned short*)pqbuf + b0);
        const ushort4 vb = *(const ushort4*)((const unsigned short*)pqbuf + b0 + HWsz);
        a0[0] = bf2f(va.x); a0[1] = bf2f(va.y); a0[2] = bf2f(va.z); a0[3] = bf2f(va.w);
        b1[0] = bf2f(vb.x); b1[1] = bf2f(vb.y); b1[2] = bf2f(vb.z); b1[3] = bf2f(vb.w);
      } else {
        const float4 va = *(const float4*)((const float*)pqbuf + b0);
        const float4 vb = *(const float4*)((const float*)pqbuf + b0 + HWsz);
        a0[0] = va.x; a0[1] = va.y; a0[2] = va.z; a0[3] = va.w;
        b1[0] = vb.x; b1[1] = vb.y; b1[2] = vb.z; b1[3] = vb.w;
      }
#pragma unroll
      for (int i = 0; i < 4; ++i) {
        const int j = 4 * g + i;
        const unsigned lo = f2bf(dq(a0[i], d0, s0, i0));
        const unsigned hi = f2bf(dq(b1[i], d1, s1, i1));
        ldsB[j * 20 + ((sq ^ ((j >> 3) & 3)) << 2) + c2] = lo | (hi << 16);
      }
    }
    __syncthreads();

    bf16x8 afr[4];
#pragma unroll
    for (int mt = 0; mt < 4; ++mt) {
      const int row = 64 * wv + 16 * mt + r15;
      afr[mt] = *(const bf16x8*)(uA + row * CH + kc * KB + q * 8);
    }
#pragma unroll
    for (int nt = 0; nt < 4; ++nt) {
      const int j = nt * 16 + r15;
      const bf16x8 bfr = *(const bf16x8*)((const unsigned short*)ldsB +
                                          (size_t)j * 40 + ((q ^ ((j >> 3) & 3)) << 3));
#pragma unroll
      for (int mt = 0; mt < 4; ++mt)
        acc[mt][nt] = __builtin_amdgcn_mfma_f32_16x16x32_bf16(afr[mt], bfr, acc[mt][nt], 0, 0, 0);
    }
  }

#pragma unroll
  for (int mt = 0; mt < 4; ++mt) {
#pragma unroll
    for (int reg = 0; reg < 4; ++reg) {
      const int row = 64 * wv + 16 * mt + 4 * q + reg;
      const float cr = st->corr[row];
      const size_t obase = ((size_t)(n * CH + row)) * HWsz + hw0;
#pragma unroll
      for (int nt = 0; nt < 4; ++nt)
        out[obase + nt * 16 + r15] = acc[mt][nt][reg] + cr;
    }
  }
}

extern "C" void kernel_launch(void* const* d_in, const int* in_sizes, int n_in,
                              void* d_out, int out_size, void* d_ws, size_t ws_size,
                              hipStream_t stream) {
  const float* x  = (const float*)d_in[0];
  const float* u  = (const float*)d_in[1];
  const float* cv = (const float*)d_in[2];
  float* out = (float*)d_out;
  Stats* st = (Stats*)d_ws;

  const size_t pq_off = (sizeof(Stats) + 255) & ~(size_t)255;
  const bool bf = ws_size >= pq_off + (size_t)CH * COLS * 2;
  void* pq = bf ? (void*)((char*)d_ws + pq_off) : (void*)out;

  const int gemm_blocks = NIMG * (HWsz / TN);  // 1568

  k_init<<<CH, CH, 0, stream>>>(u, st);
  k_relusum<<<NIMG * CH, 256, 0, stream>>>(x, st);
  k_mn_poff<<<1, CH, 0, stream>>>(u, st);
  if (bf) k_gemm1<true ><<<gemm_blocks, 256, 0, stream>>>(x, cv, st, pq);
  else    k_gemm1<false><<<gemm_blocks, 256, 0, stream>>>(x, cv, st, pq);
  k_finalize<<<1, CH, 0, stream>>>(st);
  if (bf) k_qsum<true ><<<NIMG * CH, 256, 0, stream>>>(pq, st);
  else    k_qsum<false><<<NIMG * CH, 256, 0, stream>>>(pq, st);
  k_corr<<<1, CH, 0, stream>>>(u, st);
  if (bf) k_gemm2<true ><<<gemm_blocks, 256, 0, stream>>>(pq, st, out);
  else    k_gemm2<false><<<gemm_blocks, 256, 0, stream>>>(pq, st, out);
}